// Round 1
// baseline (4014.286 us; speedup 1.0000x reference)
//
#include <hip/hip_runtime.h>
#include <cstdint>
#include <cstddef>

#define DEV __device__ __forceinline__

constexpr int B_  = 2;
constexpr int J_  = 24;
constexpr int D_  = 32;
constexpr int V_  = 32768;       // 32*32*32
constexpr int JD_ = J_ * D_;     // 768
constexpr int NI_ = 10;
constexpr long long ANN = 50331648LL;  // B*J*D*V elements of each system matrix

DEV float bflo(unsigned q){ return __uint_as_float(q << 16); }
DEV float bfhi(unsigned q){ return __uint_as_float(q & 0xffff0000u); }
DEV unsigned short f2bf(float f){
  unsigned u = __float_as_uint(f);
  unsigned r = (u + 0x7fffu + ((u >> 16) & 1u)) >> 16;   // RNE
  return (unsigned short)r;
}

// ---------------- fp32 -> bf16 convert (8 elems/thread) ----------------
__global__ __launch_bounds__(256) void k_convert(const float* __restrict__ src,
                                                 unsigned short* __restrict__ dst, int n8){
  int t = blockIdx.x * 256 + threadIdx.x;
  if (t >= n8) return;
  const float4* s4 = (const float4*)src;
  float4 a = s4[2*t], b = s4[2*t+1];
  uint4 o;
  o.x = (unsigned)f2bf(a.x) | ((unsigned)f2bf(a.y) << 16);
  o.y = (unsigned)f2bf(a.z) | ((unsigned)f2bf(a.w) << 16);
  o.z = (unsigned)f2bf(b.x) | ((unsigned)f2bf(b.y) << 16);
  o.w = (unsigned)f2bf(b.z) | ((unsigned)f2bf(b.w) << 16);
  ((uint4*)dst)[t] = o;
}

// ---------------- Fortran-order flatten of primal channel 1 ----------------
// f[b, x*1024+y*32+z] = primal[b,1,z,y,x]
__global__ __launch_bounds__(256) void k_permute_f(const float* __restrict__ primal,
                                                   float* __restrict__ f){
  const int t = blockIdx.x * 256 + threadIdx.x;       // B*V threads
  const int b = t >> 15, v = t & 32767;
  const int x = v >> 10, y = (v >> 5) & 31, z = v & 31;
  f[t] = primal[((b*5 + 1) << 15) + (z << 10) + (y << 5) + x];
}

// ---------------- evalop1[b,j,d] = sum_v An[b,j,d,v] * f[b,v] ----------------
__global__ __launch_bounds__(256) void k_evalop1_bf(const unsigned short* __restrict__ AnB,
                                                    const float* __restrict__ f_flat,
                                                    float* __restrict__ ev1){
  const int jd = blockIdx.x, b = blockIdx.y;
  const int row = b * JD_ + jd;
  const uint4*  ap = (const uint4*)(AnB + (size_t)row * V_);
  const float4* fp = (const float4*)(f_flat + b * V_);
  float acc = 0.0f;
  for (int i = threadIdx.x; i < V_/8; i += 256){
    uint4 q = ap[i];
    float4 fa = fp[2*i], fb = fp[2*i+1];
    acc += bflo(q.x)*fa.x + bfhi(q.x)*fa.y + bflo(q.y)*fa.z + bfhi(q.y)*fa.w;
    acc += bflo(q.z)*fb.x + bfhi(q.z)*fb.y + bflo(q.w)*fb.z + bfhi(q.w)*fb.w;
  }
  #pragma unroll
  for (int off = 32; off > 0; off >>= 1) acc += __shfl_down(acc, off);
  __shared__ float red[4];
  if ((threadIdx.x & 63) == 0) red[threadIdx.x >> 6] = acc;
  __syncthreads();
  if (threadIdx.x == 0) ev1[row] = red[0] + red[1] + red[2] + red[3];
}

__global__ __launch_bounds__(256) void k_evalop1_f32(const float* __restrict__ An,
                                                     const float* __restrict__ f_flat,
                                                     float* __restrict__ ev1){
  const int jd = blockIdx.x, b = blockIdx.y;
  const int row = b * JD_ + jd;
  const float4* ap = (const float4*)(An + (size_t)row * V_);
  const float4* fp = (const float4*)(f_flat + b * V_);
  float acc = 0.0f;
  for (int i = threadIdx.x; i < V_/4; i += 256){
    float4 av = ap[i], fv = fp[i];
    acc += av.x*fv.x + av.y*fv.y + av.z*fv.z + av.w*fv.w;
  }
  #pragma unroll
  for (int off = 32; off > 0; off >>= 1) acc += __shfl_down(acc, off);
  __shared__ float red[4];
  if ((threadIdx.x & 63) == 0) red[threadIdx.x >> 6] = acc;
  __syncthreads();
  if (threadIdx.x == 0) ev1[row] = red[0] + red[1] + red[2] + red[3];
}

// ---------------- 3x3 conv2d SAME over (J,D) ----------------
// CIN==7 -> input is virtual concat [dual(5), ev1(1), g(1)]
template<int CIN, int COUT, bool PRELU, bool ADDTO>
__global__ __launch_bounds__(256) void k_conv2d(const float* __restrict__ in,
                                                const float* __restrict__ ev1,
                                                const float* __restrict__ g,
                                                const float* __restrict__ w,
                                                const float* __restrict__ bias,
                                                const float* __restrict__ alpha,
                                                float* __restrict__ out){
  const int t = blockIdx.x * 256 + threadIdx.x;   // ((b*COUT+o)*J + j)*32 + d
  const int d = t & 31;
  const int j = (t >> 5) % J_;
  const int rest = (t >> 5) / J_;
  const int o = rest % COUT;
  const int b = rest / COUT;
  float acc = bias[o];
  for (int ci = 0; ci < CIN; ci++){
    const float* ip;
    if constexpr (CIN == 7){
      ip = (ci < 5) ? (in + (b*5 + ci)*JD_) : ((ci == 5) ? (ev1 + b*JD_) : (g + b*JD_));
    } else {
      ip = in + (b*CIN + ci)*JD_;
    }
    const float* wp = w + (o*CIN + ci)*9;
    #pragma unroll
    for (int kh = 0; kh < 3; kh++){
      const int jj = j + kh - 1;
      if ((unsigned)jj < (unsigned)J_){
        #pragma unroll
        for (int kw = 0; kw < 3; kw++){
          const int dd = d + kw - 1;
          if ((unsigned)dd < 32u)
            acc += ip[jj*32 + dd] * wp[kh*3 + kw];
        }
      }
    }
  }
  if constexpr (PRELU){
    const float a = alpha[0];
    acc = (acc >= 0.0f) ? acc : a * acc;
  }
  if constexpr (ADDTO) out[t] += acc;
  else                 out[t] = acc;
}

// ---------------- back[b,v] = sum_{j,d} A[b,j,v,d]*dual[b,0,j,d], written permuted ----------------
// wave: 8 v's x 8 d-quads (dq covers 4 d). Coalesced 16B(f32)/8B(bf16) per lane.
__global__ __launch_bounds__(256) void k_back_bf(const unsigned short* __restrict__ AB,
                                                 const float* __restrict__ dual,
                                                 float* __restrict__ ev2){
  __shared__ float wj[JD_];
  const int b = blockIdx.y;
  for (int i = threadIdx.x; i < JD_; i += 256) wj[i] = dual[b*5*JD_ + i];
  __syncthreads();
  const int lane = threadIdx.x & 63;
  const int wave = threadIdx.x >> 6;
  const int dq = lane & 7;
  const int vi = lane >> 3;
  const int v = blockIdx.x * 32 + wave * 8 + vi;
  float acc = 0.0f;
  for (int j = 0; j < J_; j++){
    const unsigned short* rp = AB + ((size_t)(b*J_ + j) * V_ + v) * 32 + dq*4;
    uint2 q = *(const uint2*)rp;
    const float* wp = &wj[j*32 + dq*4];
    acc += bflo(q.x)*wp[0] + bfhi(q.x)*wp[1] + bflo(q.y)*wp[2] + bfhi(q.y)*wp[3];
  }
  acc += __shfl_xor(acc, 1);
  acc += __shfl_xor(acc, 2);
  acc += __shfl_xor(acc, 4);
  if (dq == 0){
    const int xx = v >> 10, yy = (v >> 5) & 31, zz = v & 31;
    ev2[(b << 15) + (zz << 10) + (yy << 5) + xx] = acc;
  }
}

__global__ __launch_bounds__(256) void k_back_f32(const float* __restrict__ A,
                                                  const float* __restrict__ dual,
                                                  float* __restrict__ ev2){
  __shared__ float wj[JD_];
  const int b = blockIdx.y;
  for (int i = threadIdx.x; i < JD_; i += 256) wj[i] = dual[b*5*JD_ + i];
  __syncthreads();
  const int lane = threadIdx.x & 63;
  const int wave = threadIdx.x >> 6;
  const int dq = lane & 7;
  const int vi = lane >> 3;
  const int v = blockIdx.x * 32 + wave * 8 + vi;
  float acc = 0.0f;
  for (int j = 0; j < J_; j++){
    const float* rp = A + ((size_t)(b*J_ + j) * V_ + v) * 32 + dq*4;
    float4 av = *(const float4*)rp;
    const float* wp = &wj[j*32 + dq*4];
    acc += av.x*wp[0] + av.y*wp[1] + av.z*wp[2] + av.w*wp[3];
  }
  acc += __shfl_xor(acc, 1);
  acc += __shfl_xor(acc, 2);
  acc += __shfl_xor(acc, 4);
  if (dq == 0){
    const int xx = v >> 10, yy = (v >> 5) & 31, zz = v & 31;
    ev2[(b << 15) + (zz << 10) + (yy << 5) + xx] = acc;
  }
}

// ---------------- 3x3x3 conv3d SAME over (Z,Y,X) ----------------
// thread = 1 spatial point x CH couts; weights staged per-cin-chunk in LDS as [ck][tap][cout]
// L1IN -> input is virtual concat [primal(5), ev2(1)]
template<int CIN, int COUT, int COSPLIT, bool PRELU, bool ADDTO, bool L1IN>
__global__ __launch_bounds__(256) void k_conv3d(const float* __restrict__ in,
                                                const float* __restrict__ ev2,
                                                const float* __restrict__ w,
                                                const float* __restrict__ bias,
                                                const float* __restrict__ alpha,
                                                float* __restrict__ out){
  constexpr int PPB = 256 / COSPLIT;       // points per block
  constexpr int CH  = COUT / COSPLIT;      // couts per thread
  constexpr int CK  = (CIN < 8) ? CIN : 8; // cin chunk
  constexpr int NCHUNK = CIN / CK;
  __shared__ __align__(16) float lw[CK * 27 * COUT];

  const int tid = threadIdx.x;
  const int p_local = tid % PPB;
  const int h = tid / PPB;
  const int P = blockIdx.x * PPB + p_local;
  const int b = P >> 15;
  const int s = P & 32767;
  const int z = s >> 10, y = (s >> 5) & 31, x = s & 31;

  float acc[CH];
  #pragma unroll
  for (int i = 0; i < CH; i++) acc[i] = bias[h*CH + i];

  for (int c0 = 0; c0 < NCHUNK; c0++){
    const int ci0 = c0 * CK;
    __syncthreads();
    for (int idx = tid; idx < CK*27*COUT; idx += 256){
      const int co  = idx % COUT;
      const int r   = idx / COUT;
      const int tap = r % 27;
      const int ck  = r / 27;
      lw[idx] = w[(co*CIN + ci0 + ck)*27 + tap];
    }
    __syncthreads();
    for (int ck = 0; ck < CK; ck++){
      const int ci = ci0 + ck;
      const float* ip;
      if constexpr (L1IN){
        ip = (ci < 5) ? (in + ((b*5 + ci) << 15)) : (ev2 + (b << 15));
      } else {
        ip = in + ((b*CIN + ci) << 15);
      }
      #pragma unroll
      for (int kz = 0; kz < 3; kz++){
        const int zz = z + kz - 1;
        const bool vz = (unsigned)zz < 32u;
        #pragma unroll
        for (int ky = 0; ky < 3; ky++){
          const int yy = y + ky - 1;
          const bool vy = (unsigned)yy < 32u;
          #pragma unroll
          for (int kx = 0; kx < 3; kx++){
            const int xx = x + kx - 1;
            float v = 0.0f;
            if (vz && vy && ((unsigned)xx < 32u))
              v = ip[(zz << 10) + (yy << 5) + xx];
            const float* wr = &lw[(ck*27 + (kz*3 + ky)*3 + kx)*COUT + h*CH];
            #pragma unroll
            for (int co = 0; co < CH; co++) acc[co] += v * wr[co];
          }
        }
      }
    }
  }

  if constexpr (PRELU){
    const float a = alpha[0];
    #pragma unroll
    for (int i = 0; i < CH; i++) acc[i] = (acc[i] >= 0.0f) ? acc[i] : a * acc[i];
  }
  #pragma unroll
  for (int i = 0; i < CH; i++){
    const int co = h*CH + i;
    float* op = out + (((size_t)(b*COUT + co)) << 15) + s;
    if constexpr (ADDTO) *op += acc[i];
    else                 *op = acc[i];
  }
}

// ---------------- final output: primal channel 0 ----------------
__global__ __launch_bounds__(256) void k_output(const float* __restrict__ primal,
                                                float* __restrict__ out){
  const int t = blockIdx.x * 256 + threadIdx.x;  // B*V
  const int b = t >> 15, s = t & 32767;
  out[t] = primal[((b*5) << 15) + s];
}

extern "C" void kernel_launch(void* const* d_in, const int* in_sizes, int n_in,
                              void* d_out, int out_size, void* d_ws, size_t ws_size,
                              hipStream_t stream){
  const float* dual_in   = (const float*)d_in[0];
  const float* primal_in = (const float*)d_in[1];
  const float* g    = (const float*)d_in[2];
  const float* An   = (const float*)d_in[3];
  const float* A    = (const float*)d_in[4];
  const float* dw1  = (const float*)d_in[5];
  const float* db1  = (const float*)d_in[6];
  const float* da1  = (const float*)d_in[7];
  const float* dw2  = (const float*)d_in[8];
  const float* db2  = (const float*)d_in[9];
  const float* da2  = (const float*)d_in[10];
  const float* dw3  = (const float*)d_in[11];
  const float* db3  = (const float*)d_in[12];
  const float* pw1  = (const float*)d_in[13];
  const float* pb1  = (const float*)d_in[14];
  const float* pa1  = (const float*)d_in[15];
  const float* pw2  = (const float*)d_in[16];
  const float* pb2  = (const float*)d_in[17];
  const float* pa2  = (const float*)d_in[18];
  const float* pw3  = (const float*)d_in[19];
  const float* pb3  = (const float*)d_in[20];

  const size_t bf_bytes = (size_t)ANN * 2u * 2u;  // two bf16 matrices
  const size_t f_floats = 7680 + 327680 + 65536 + 1536 + 49152 + 49152 + 65536
                        + 2097152 + 2097152;
  const bool use_bf16 = ws_size >= bf_bytes + f_floats * 4;

  unsigned short* AnB = (unsigned short*)d_ws;
  unsigned short* AB  = AnB + ANN;
  float* base = use_bf16 ? (float*)(AB + ANN) : (float*)d_ws;
  float* dual   = base;             // 7680
  float* primal = dual + 7680;      // 327680
  float* f_flat = primal + 327680;  // 65536
  float* ev1    = f_flat + 65536;   // 1536
  float* h2a    = ev1 + 1536;       // 49152
  float* h2b    = h2a + 49152;      // 49152
  float* ev2    = h2b + 49152;      // 65536   (stored [B,Z,Y,X])
  float* h3a    = ev2 + 65536;      // 2097152
  float* h3b    = h3a + 2097152;    // 2097152

  hipMemcpyAsync(dual, dual_in, 7680 * sizeof(float), hipMemcpyDeviceToDevice, stream);
  hipMemcpyAsync(primal, primal_in, 327680 * sizeof(float), hipMemcpyDeviceToDevice, stream);

  if (use_bf16){
    const int n8 = (int)(ANN / 8);
    k_convert<<<n8 / 256, 256, 0, stream>>>(An, AnB, n8);
    k_convert<<<n8 / 256, 256, 0, stream>>>(A,  AB,  n8);
  }

  for (int k = 0; k < NI_; k++){
    k_permute_f<<<256, 256, 0, stream>>>(primal, f_flat);
    if (use_bf16) k_evalop1_bf <<<dim3(JD_, B_), 256, 0, stream>>>(AnB, f_flat, ev1);
    else          k_evalop1_f32<<<dim3(JD_, B_), 256, 0, stream>>>(An,  f_flat, ev1);

    k_conv2d<7, 32, true,  false><<<192, 256, 0, stream>>>(dual, ev1, g,
        dw1 + k*2016, db1 + k*32, da1 + k, h2a);
    k_conv2d<32, 32, true, false><<<192, 256, 0, stream>>>(h2a, nullptr, nullptr,
        dw2 + k*9216, db2 + k*32, da2 + k, h2b);
    k_conv2d<32, 5, false, true><<<30, 256, 0, stream>>>(h2b, nullptr, nullptr,
        dw3 + k*1440, db3 + k*5, nullptr, dual);

    if (use_bf16) k_back_bf <<<dim3(V_/32, B_), 256, 0, stream>>>(AB, dual, ev2);
    else          k_back_f32<<<dim3(V_/32, B_), 256, 0, stream>>>(A,  dual, ev2);

    k_conv3d<6, 32, 2, true,  false, true ><<<512, 256, 0, stream>>>(primal, ev2,
        pw1 + k*5184, pb1 + k*32, pa1 + k, h3a);
    k_conv3d<32, 32, 2, true, false, false><<<512, 256, 0, stream>>>(h3a, nullptr,
        pw2 + k*27648, pb2 + k*32, pa2 + k, h3b);
    k_conv3d<32, 5, 1, false, true,  false><<<256, 256, 0, stream>>>(h3b, nullptr,
        pw3 + k*4320, pb3 + k*5, nullptr, primal);
  }

  k_output<<<256, 256, 0, stream>>>(primal, (float*)d_out);
}